// Round 13
// baseline (243.487 us; speedup 1.0000x reference)
//
#include <hip/hip_runtime.h>
#include <stdint.h>

typedef unsigned long long u64;
typedef unsigned int u32;

#define NB 8
#define NN 2048
#define NC 80
#define ROW 84
#define OUT_K 200
#define IOU_T 0.5f
#define SCORE_T 0.01f
#define TGT 896
#define POOL 1024

// ---- compare-exchange, descending network, direction from global index ----
__device__ __forceinline__ void ce_desc(u64* a, int i, int j, int k) {
    u64 a0 = a[i], a1 = a[i + j];
    bool up = ((i & k) == 0);
    if (up ? (a0 < a1) : (a0 > a1)) { a[i] = a1; a[i + j] = a0; }
}

// register compare-exchange; up=true -> larger first (descending pair)
__device__ __forceinline__ void ceg(u64& x, u64& y, bool up) {
    u64 a0 = x, a1 = y;
    if (up ? (a0 < a1) : (a0 > a1)) { x = a1; y = a0; }
}

// wave-local rounds on a 512-elem segment (4 CE/lane/round), j<=256
__device__ __forceinline__ void wave_rounds512(u64* a, int base, int k, int jhi, int lane) {
    for (int j = jhi; j > 0; j >>= 1) {
        #pragma unroll
        for (int p = 0; p < 4; p++) {
            int r = lane + p * 64;
            int low = r & (j - 1);
            int high = (r & ~(j - 1)) << 1;
            ce_desc(a, base + (high | low), j, k);
        }
        __builtin_amdgcn_wave_barrier();
    }
}

// wave-local rounds on a 256-elem segment; k=0x40000000 -> all-descending merge
__device__ __forceinline__ void wave_rounds256(u64* a, int base, int k, int jhi, int lane) {
    for (int j = jhi; j > 0; j >>= 1) {
        #pragma unroll
        for (int p = 0; p < 2; p++) {
            int r = lane + p * 64;
            int low = r & (j - 1);
            int high = (r & ~(j - 1)) << 1;
            ce_desc(a, base + (high | low), j, k);
        }
        __builtin_amdgcn_wave_barrier();
    }
}

// max-combine two desc-sorted 256-runs (base, base+off) -> top-256 sorted desc
__device__ __forceinline__ void pair_merge256(u64* a, int base, int off, int lane) {
    #pragma unroll
    for (int p0 = 0; p0 < 4; p0++) {
        int p = lane + p0 * 64;
        u64 xv = a[base + p];
        u64 yv = a[base + off + 255 - p];
        a[base + p] = xv > yv ? xv : yv;
    }
    __builtin_amdgcn_wave_barrier();
    wave_rounds256(a, base, 0x40000000, 128, lane);
}

// full hybrid bitonic sort of 2048 (desc) — identical network to rounds 4-12
__device__ __forceinline__ void sort2048(u64* key, int tid, int lane, int wv) {
    const int base = wv * 512;
    for (int k = 2; k <= 512; k <<= 1)
        wave_rounds512(key, base, k, k >> 1, lane);
    __syncthreads();
    #pragma unroll
    for (int p = 0; p < 4; p++) {
        int r = tid + p * 256;
        int low = r & 511, high = (r & ~511) << 1;
        ce_desc(key, high | low, 512, 1024);
    }
    __syncthreads();
    wave_rounds512(key, base, 1024, 256, lane);
    __syncthreads();
    #pragma unroll
    for (int p = 0; p < 4; p++) {
        int r = tid + p * 256;
        int low = r & 1023, high = (r & ~1023) << 1;
        ce_desc(key, high | low, 1024, 2048);
    }
    __syncthreads();
    #pragma unroll
    for (int p = 0; p < 4; p++) {
        int r = tid + p * 256;
        int low = r & 511, high = (r & ~511) << 1;
        ce_desc(key, high | low, 512, 2048);
    }
    __syncthreads();
    wave_rounds512(key, base, 2048, 256, lane);
    __syncthreads();
}

// bitonic sort of 1024 (desc): 4 elems/thread, register-fused j<=2 rounds
__device__ __forceinline__ void sort1024(u64* a, int tid, int lane, int wv) {
    const int t4 = tid * 4;
    const int sb = wv * 256;
    {
        u64 v0 = a[t4], v1 = a[t4 + 1], v2 = a[t4 + 2], v3 = a[t4 + 3];
        ceg(v0, v1, true);
        ceg(v2, v3, false);
        const bool d4 = ((t4 & 4) == 0);
        ceg(v0, v2, d4); ceg(v1, v3, d4);
        ceg(v0, v1, d4); ceg(v2, v3, d4);
        a[t4] = v0; a[t4 + 1] = v1; a[t4 + 2] = v2; a[t4 + 3] = v3;
    }
    __builtin_amdgcn_wave_barrier();
    for (int k = 8; k <= 256; k <<= 1) {
        for (int j = k >> 1; j >= 4; j >>= 1) {
            #pragma unroll
            for (int p = 0; p < 2; p++) {
                int r = lane + p * 64;
                int low = r & (j - 1);
                int high = (r & ~(j - 1)) << 1;
                ce_desc(a, sb + (high | low), j, k);
            }
            __builtin_amdgcn_wave_barrier();
        }
        {
            u64 v0 = a[t4], v1 = a[t4 + 1], v2 = a[t4 + 2], v3 = a[t4 + 3];
            const bool d = ((t4 & k) == 0);
            ceg(v0, v2, d); ceg(v1, v3, d);
            ceg(v0, v1, d); ceg(v2, v3, d);
            a[t4] = v0; a[t4 + 1] = v1; a[t4 + 2] = v2; a[t4 + 3] = v3;
        }
        __builtin_amdgcn_wave_barrier();
    }
    __syncthreads();
    #pragma unroll
    for (int p = 0; p < 2; p++) {
        int r = tid + p * 256;
        int low = r & 255, high = (r & ~255) << 1;
        ce_desc(a, high | low, 256, 512);
    }
    __syncthreads();
    for (int j = 128; j >= 4; j >>= 1) {
        #pragma unroll
        for (int p = 0; p < 2; p++) {
            int r = lane + p * 64;
            int low = r & (j - 1);
            int high = (r & ~(j - 1)) << 1;
            ce_desc(a, sb + (high | low), j, 512);
        }
        __builtin_amdgcn_wave_barrier();
    }
    {
        u64 v0 = a[t4], v1 = a[t4 + 1], v2 = a[t4 + 2], v3 = a[t4 + 3];
        const bool d = ((t4 & 512) == 0);
        ceg(v0, v2, d); ceg(v1, v3, d);
        ceg(v0, v1, d); ceg(v2, v3, d);
        a[t4] = v0; a[t4 + 1] = v1; a[t4 + 2] = v2; a[t4 + 3] = v3;
    }
    __syncthreads();
    #pragma unroll
    for (int p = 0; p < 2; p++) {
        int r = tid + p * 256;
        int low = r & 511, high = (r & ~511) << 1;
        ce_desc(a, high | low, 512, 1024);
    }
    __syncthreads();
    #pragma unroll
    for (int p = 0; p < 2; p++) {
        int r = tid + p * 256;
        int low = r & 255, high = (r & ~255) << 1;
        ce_desc(a, high | low, 256, 1024);
    }
    __syncthreads();
    for (int j = 128; j >= 4; j >>= 1) {
        #pragma unroll
        for (int p = 0; p < 2; p++) {
            int r = lane + p * 64;
            int low = r & (j - 1);
            int high = (r & ~(j - 1)) << 1;
            ce_desc(a, sb + (high | low), j, 1024);
        }
        __builtin_amdgcn_wave_barrier();
    }
    {
        u64 v0 = a[t4], v1 = a[t4 + 1], v2 = a[t4 + 2], v3 = a[t4 + 3];
        const bool d = ((t4 & 1024) == 0);
        ceg(v0, v2, d); ceg(v1, v3, d);
        ceg(v0, v1, d); ceg(v2, v3, d);
        a[t4] = v0; a[t4 + 1] = v1; a[t4 + 2] = v2; a[t4 + 3] = v3;
    }
    __syncthreads();
}

// exact reference-order IoU > 0.5 test (byte-identical to passing rounds 3-12)
__device__ __forceinline__ bool iou_gt_half(float4 a, float aa, float4 b, float ab) {
    float ltx = fmaxf(a.x, b.x);
    float lty = fmaxf(a.y, b.y);
    float rbx = fminf(a.z, b.z);
    float rby = fminf(a.w, b.w);
    float wd = fmaxf(__fsub_rn(rbx, ltx), 0.0f);
    float hd = fmaxf(__fsub_rn(rby, lty), 0.0f);
    float inter = __fmul_rn(wd, hd);
    float uni = __fsub_rn(__fadd_rn(aa, ab), inter);
    float m = fmaxf(uni, 1e-8f);
    float d2 = __fmul_rn(2.0f, inter);
    bool sup = d2 > m;
    if (sup && (__fsub_rn(d2, m) <= __fmul_rn(m, 1.2e-7f)))
        sup = __fdiv_rn(inter, m) > IOU_T;
    return sup;
}

__device__ __forceinline__ float bcast(float v, int sl) {
    return __int_as_float(__builtin_amdgcn_readlane(__float_as_int(v), sl));
}

// chunked greedy, 128 candidates per phase (2/lane). Same acceptance order
// as the 64-chunk version: word0 positions all precede word1; ctz order
// within each word = ascending sorted position. Accepted boxes suppress
// both words. Returns kept count (uniform).
__device__ __forceinline__ int greedy128(const u64* cand, int maxph, const float* xb,
        float4* kept_box, float* kept_area, u64* kept_key,
        u64* s_sup0, u64* s_sup1, int* s_kept, int* s_done,
        int tid, int lane, int wv, int keptc_in) {
    if (tid == 0) { *s_kept = keptc_in; *s_done = 0; }
    __syncthreads();
    int keptc = keptc_in;
    for (int ph = 0; ph < maxph; ph++) {
        const int n0 = ph * 128 + lane;
        const int n1 = n0 + 64;
        u64 k0 = cand[n0], k1 = cand[n1];
        bool v0 = __uint_as_float((u32)(k0 >> 32)) > SCORE_T;
        bool v1 = __uint_as_float((u32)(k1 >> 32)) > SCORE_T;
        u64 vb0 = __ballot(v0), vb1 = __ballot(v1);
        if (vb0 == 0ULL) break;            // sorted: nothing valid here or later

        u32 o0 = 2047u - (u32)(k0 & 0x7FFu);
        u32 o1 = 2047u - (u32)(k1 & 0x7FFu);
        float4 b0 = *(const float4*)(xb + (size_t)o0 * ROW);
        float4 b1 = *(const float4*)(xb + (size_t)o1 * ROW);
        float a0 = __fmul_rn(__fsub_rn(b0.z, b0.x), __fsub_rn(b0.w, b0.y));
        float a1 = __fmul_rn(__fsub_rn(b1.z, b1.x), __fsub_rn(b1.w, b1.y));

        // kept-test both candidates vs kept[t], t ≡ wv (mod 4), x4 batched
        bool sup0 = false, sup1 = false;
        int t = wv;
        for (; t + 12 < keptc; t += 16) {
            float4 kb0 = kept_box[t],     kb1 = kept_box[t + 4];
            float4 kb2 = kept_box[t + 8], kb3 = kept_box[t + 12];
            float ka0 = kept_area[t],     ka1 = kept_area[t + 4];
            float ka2 = kept_area[t + 8], ka3 = kept_area[t + 12];
            sup0 = sup0 | ((iou_gt_half(b0, a0, kb0, ka0) | iou_gt_half(b0, a0, kb1, ka1))
                         | (iou_gt_half(b0, a0, kb2, ka2) | iou_gt_half(b0, a0, kb3, ka3)));
            sup1 = sup1 | ((iou_gt_half(b1, a1, kb0, ka0) | iou_gt_half(b1, a1, kb1, ka1))
                         | (iou_gt_half(b1, a1, kb2, ka2) | iou_gt_half(b1, a1, kb3, ka3)));
        }
        for (; t < keptc; t += 4) {
            float4 kb = kept_box[t]; float ka = kept_area[t];
            sup0 = sup0 | iou_gt_half(b0, a0, kb, ka);
            sup1 = sup1 | iou_gt_half(b1, a1, kb, ka);
        }
        if (lane == 0) { s_sup0[wv] = __ballot(sup0); s_sup1[wv] = __ballot(sup1); }
        else { __ballot(sup0); __ballot(sup1); }
        __syncthreads();                   // B1

        if (wv == 0) {
            u64 al0 = vb0 & ~(s_sup0[0] | s_sup0[1] | s_sup0[2] | s_sup0[3]);
            u64 al1 = vb1 & ~(s_sup1[0] | s_sup1[1] | s_sup1[2] | s_sup1[3]);
            int kept = keptc;
            int done = 0;
            while (al0) {                  // word 0 scan
                int bsel = (int)__builtin_ctzll(al0);
                if (lane == bsel) {
                    kept_key[kept] = k0; kept_box[kept] = b0; kept_area[kept] = a0;
                }
                kept++;
                if (kept >= OUT_K) { done = 1; break; }
                al0 &= al0 - 1;
                if ((al0 | al1) == 0ULL) break;
                float4 pb = make_float4(bcast(b0.x, bsel), bcast(b0.y, bsel),
                                        bcast(b0.z, bsel), bcast(b0.w, bsel));
                float pa = bcast(a0, bsel);
                al0 &= ~__ballot(iou_gt_half(b0, a0, pb, pa));
                al1 &= ~__ballot(iou_gt_half(b1, a1, pb, pa));
            }
            if (!done) while (al1) {       // word 1 scan
                int bsel = (int)__builtin_ctzll(al1);
                if (lane == bsel) {
                    kept_key[kept] = k1; kept_box[kept] = b1; kept_area[kept] = a1;
                }
                kept++;
                if (kept >= OUT_K) { done = 1; break; }
                al1 &= al1 - 1;
                if (al1 == 0ULL) break;
                float4 pb = make_float4(bcast(b1.x, bsel), bcast(b1.y, bsel),
                                        bcast(b1.z, bsel), bcast(b1.w, bsel));
                float pa = bcast(a1, bsel);
                al1 &= ~__ballot(iou_gt_half(b1, a1, pb, pa));
            }
            if (lane == 0) { *s_kept = kept; if (done) *s_done = 1; }
        }
        __syncthreads();                   // B2
        keptc = *s_kept;
        if (*s_done) break;
        if (__popcll(vb1) < 64) break;     // sorted: nothing valid beyond
    }
    __syncthreads();
    return keptc;
}

// ---- Kernel A: histogram-select -> sort1024 -> greedy128 (+continuation) ----
__global__ __launch_bounds__(256) void nms_kernel(
        const float* __restrict__ x, u64* __restrict__ cand_key) {
    const int bc = blockIdx.x;
    const int b = bc / NC;
    const int c = bc % NC;
    const int tid = threadIdx.x;
    const int lane = tid & 63;
    const int wv = tid >> 6;

    __shared__ __align__(16) u64 arr[2048];
    u64* comp = arr;
    u32* hist = (u32*)(arr + 1024);
    __shared__ float4 kept_box[OUT_K];
    __shared__ float kept_area[OUT_K];
    __shared__ u64 kept_key[OUT_K];
    __shared__ u64 s_sup0[4], s_sup1[4];
    __shared__ u32 s_wsum[4];
    __shared__ u32 s_cnt, s_m;
    __shared__ int s_kept, s_done, s_thr;

    const float* xb = x + (size_t)b * NN * ROW;

    hist[tid] = 0;
    __syncthreads();
    float scv[8];
    #pragma unroll
    for (int w = 0; w < 8; w++) {
        int n = w * 256 + tid;
        float sc = xb[n * ROW + 4 + c];
        scv[w] = sc;
        int bin = (int)(sc * 256.0f); bin = bin > 255 ? 255 : bin;
        atomicAdd(&hist[bin], 1u);
    }
    __syncthreads();

    u32 cnt_mine = hist[tid];
    u32 incl = cnt_mine;
    #pragma unroll
    for (int off = 1; off < 64; off <<= 1) {
        u32 v = __shfl_down(incl, off, 64);
        if (lane + off < 64) incl += v;
    }
    if (lane == 0) s_wsum[wv] = incl;
    __syncthreads();
    u32 above = 0;
    #pragma unroll
    for (int w = 0; w < 4; w++) above += (w > wv) ? s_wsum[w] : 0;
    const u32 suf = incl + above;

    if (tid == 0) s_thr = 2;
    __syncthreads();
    if (suf >= TGT && suf - cnt_mine < TGT) s_thr = tid;
    __syncthreads();
    int t1 = s_thr;
    if (tid == t1) s_m = suf;
    __syncthreads();
    u32 m_tot = s_m;

    bool fb = (m_tot > POOL);
    int kept = 0;
    if (!fb) {
        if (tid == 0) s_cnt = 0;
        __syncthreads();
        #pragma unroll
        for (int w = 0; w < 8; w++) {
            float sc = scv[w];
            int bin = (int)(sc * 256.0f); bin = bin > 255 ? 255 : bin;
            if (bin >= t1) {
                int n = w * 256 + tid;
                u32 p = atomicAdd(&s_cnt, 1u);
                comp[p] = ((u64)__float_as_uint(sc) << 32) | (u64)(2047 - n);
            }
        }
        __syncthreads();
        for (int i = tid; i < POOL; i += 256) if (i >= (int)m_tot) comp[i] = 0ULL;
        __syncthreads();
        sort1024(comp, tid, lane, wv);
        kept = greedy128(comp, POOL / 128, xb, kept_box, kept_area, kept_key,
                         s_sup0, s_sup1, &s_kept, &s_done, tid, lane, wv, 0);

        while (kept < OUT_K && t1 > 2) {
            u32 T2 = m_tot + TGT;
            if (tid == 0) s_thr = 2;
            __syncthreads();
            if (suf >= T2 && suf - cnt_mine < T2) s_thr = tid;
            __syncthreads();
            int t2 = s_thr;
            if (tid == t2) s_m = suf;
            __syncthreads();
            u32 m2 = s_m;
            u32 size = m2 - m_tot;
            if (size == 0) break;
            if (size > POOL) { fb = true; break; }
            if (tid == 0) s_cnt = 0;
            __syncthreads();
            #pragma unroll
            for (int w = 0; w < 8; w++) {
                float sc = scv[w];
                int bin = (int)(sc * 256.0f); bin = bin > 255 ? 255 : bin;
                if (bin >= t2 && bin < t1) {
                    int n = w * 256 + tid;
                    u32 p = atomicAdd(&s_cnt, 1u);
                    comp[p] = ((u64)__float_as_uint(sc) << 32) | (u64)(2047 - n);
                }
            }
            __syncthreads();
            for (int i = tid; i < POOL; i += 256) if (i >= (int)size) comp[i] = 0ULL;
            __syncthreads();
            sort1024(comp, tid, lane, wv);
            kept = greedy128(comp, POOL / 128, xb, kept_box, kept_area, kept_key,
                             s_sup0, s_sup1, &s_kept, &s_done, tid, lane, wv, kept);
            m_tot = m2; t1 = t2;
        }
    }
    if (fb) {
        __syncthreads();
        #pragma unroll
        for (int w = 0; w < 8; w++) {
            int n = w * 256 + tid;
            arr[n] = ((u64)__float_as_uint(scv[w]) << 32) | (u64)(2047 - n);
        }
        __syncthreads();
        sort2048(arr, tid, lane, wv);
        kept = greedy128(arr, 16, xb, kept_box, kept_area, kept_key,
                         s_sup0, s_sup1, &s_kept, &s_done, tid, lane, wv, 0);
    }

    const int base_o = bc * OUT_K;
    if (tid < OUT_K) {
        u64 ok = 0ULL;
        if (tid < kept) {
            u64 kk = kept_key[tid];
            u32 flat = (u32)(c * OUT_K + tid);
            u32 orig = 2047u - (u32)(kk & 0x7FFu);
            ok = (kk & 0xFFFFFFFF00000000ULL) |
                 ((u64)(0x3FFFu - flat) << 11) | (u64)orig;
        }
        cand_key[base_o + tid] = ok;
    }
}

// ---- Kernel B: 8 blocks x 512 threads; 8 waves stream 10 runs each,
//      then 3-level tournament -> decode top-200 ----
__global__ __launch_bounds__(512) void topk_kernel(
        const float* __restrict__ x, const u64* __restrict__ cand_key,
        float* __restrict__ out) {
    const int b = blockIdx.x;
    const int tid = threadIdx.x;
    const int lane = tid & 63;
    const int wv = tid >> 6;          // 0..7
    __shared__ u64 seg[4096];         // per-wave 512: A=[0,256) B=[256,512)
    __shared__ u64 acc[2048];
    u64* A = seg + wv * 512;

    const u64* src0 = cand_key + (size_t)(b * NC + wv * 10) * OUT_K;

    A[lane] = src0[lane];
    A[lane + 64] = src0[lane + 64];
    A[lane + 128] = src0[lane + 128];
    A[lane + 192] = (lane + 192 < OUT_K) ? src0[lane + 192] : 0ULL;
    const u64* srcp = src0 + OUT_K;
    u64 r0 = srcp[lane];
    u64 r1 = srcp[lane + 64];
    u64 r2 = srcp[lane + 128];
    u64 r3 = (lane + 192 < OUT_K) ? srcp[lane + 192] : 0ULL;

    for (int i = 1; i < 10; i++) {
        A[256 + lane] = r0;
        A[256 + lane + 64] = r1;
        A[256 + lane + 128] = r2;
        A[256 + lane + 192] = r3;
        if (i + 1 < 10) {
            const u64* srcn = src0 + (size_t)(i + 1) * OUT_K;
            r0 = srcn[lane];
            r1 = srcn[lane + 64];
            r2 = srcn[lane + 128];
            r3 = (lane + 192 < OUT_K) ? srcn[lane + 192] : 0ULL;
        }
        __builtin_amdgcn_wave_barrier();
        pair_merge256(seg, wv * 512, 256, lane);   // A = top-256(A ∪ B)
    }

    #pragma unroll
    for (int p0 = 0; p0 < 4; p0++) {
        int p = lane + p0 * 64;
        acc[wv * 256 + p] = A[p];
    }
    __syncthreads();
    if (wv < 4) pair_merge256(acc, wv * 512, 256, lane);
    __syncthreads();
    if (wv < 2) pair_merge256(acc, wv * 1024, 512, lane);
    __syncthreads();
    if (wv == 0) pair_merge256(acc, 0, 1024, lane);
    __syncthreads();

    const float* xb = x + (size_t)b * NN * ROW;
    if (tid < OUT_K) {
        u64 kk = acc[tid];
        float* o = out + ((size_t)b * OUT_K + tid) * 6;
        if (kk == 0ULL) {
            o[0] = 0.f; o[1] = 0.f; o[2] = 0.f; o[3] = 0.f; o[4] = 0.f; o[5] = 0.f;
        } else {
            u32 lo = (u32)(kk & 0xFFFFFFFFu);
            u32 flat = 0x3FFFu - ((lo >> 11) & 0x3FFFu);
            int cls = flat / OUT_K;
            u32 n = lo & 0x7FFu;
            float scf = __uint_as_float((u32)(kk >> 32));
            float4 bx = *(const float4*)(xb + (size_t)n * ROW);
            o[0] = (float)cls;
            o[1] = scf;
            o[2] = fminf(fmaxf(bx.x, 0.0f), 1.0f);
            o[3] = fminf(fmaxf(bx.y, 0.0f), 1.0f);
            o[4] = fminf(fmaxf(bx.z, 0.0f), 1.0f);
            o[5] = fminf(fmaxf(bx.w, 0.0f), 1.0f);
        }
    }
}

extern "C" void kernel_launch(void* const* d_in, const int* in_sizes, int n_in,
                              void* d_out, int out_size, void* d_ws, size_t ws_size,
                              hipStream_t stream) {
    const float* x = (const float*)d_in[0];
    float* out = (float*)d_out;
    u64* cand_key = (u64*)d_ws;   // 8*80*200*8 = 1,024,000 B
    nms_kernel<<<NB * NC, 256, 0, stream>>>(x, cand_key);
    topk_kernel<<<NB, 512, 0, stream>>>(x, cand_key, out);
}

// Round 14
// 169.952 us; speedup vs baseline: 1.4327x; 1.4327x over previous
//
#include <hip/hip_runtime.h>
#include <stdint.h>

typedef unsigned long long u64;
typedef unsigned int u32;

#define NB 8
#define NN 2048
#define NC 80
#define ROW 84
#define OUT_K 200
#define IOU_T 0.5f
#define SCORE_T 0.01f
#define TGT 896
#define POOL 1024

// ---- compare-exchange, descending network, direction from global index ----
__device__ __forceinline__ void ce_desc(u64* a, int i, int j, int k) {
    u64 a0 = a[i], a1 = a[i + j];
    bool up = ((i & k) == 0);
    if (up ? (a0 < a1) : (a0 > a1)) { a[i] = a1; a[i + j] = a0; }
}

// register compare-exchange; up=true -> larger first (descending pair)
__device__ __forceinline__ void ceg(u64& x, u64& y, bool up) {
    u64 a0 = x, a1 = y;
    if (up ? (a0 < a1) : (a0 > a1)) { x = a1; y = a0; }
}

// wave-local rounds on a 512-elem segment (4 CE/lane/round), j<=256
__device__ __forceinline__ void wave_rounds512(u64* a, int base, int k, int jhi, int lane) {
    for (int j = jhi; j > 0; j >>= 1) {
        #pragma unroll
        for (int p = 0; p < 4; p++) {
            int r = lane + p * 64;
            int low = r & (j - 1);
            int high = (r & ~(j - 1)) << 1;
            ce_desc(a, base + (high | low), j, k);
        }
        __builtin_amdgcn_wave_barrier();
    }
}

// wave-local rounds on a 256-elem segment; k=0x40000000 -> all-descending merge
__device__ __forceinline__ void wave_rounds256(u64* a, int base, int k, int jhi, int lane) {
    for (int j = jhi; j > 0; j >>= 1) {
        #pragma unroll
        for (int p = 0; p < 2; p++) {
            int r = lane + p * 64;
            int low = r & (j - 1);
            int high = (r & ~(j - 1)) << 1;
            ce_desc(a, base + (high | low), j, k);
        }
        __builtin_amdgcn_wave_barrier();
    }
}

// max-combine two desc-sorted 256-runs (base, base+off) -> top-256 sorted desc
__device__ __forceinline__ void pair_merge256(u64* a, int base, int off, int lane) {
    #pragma unroll
    for (int p0 = 0; p0 < 4; p0++) {
        int p = lane + p0 * 64;
        u64 xv = a[base + p];
        u64 yv = a[base + off + 255 - p];
        a[base + p] = xv > yv ? xv : yv;
    }
    __builtin_amdgcn_wave_barrier();
    wave_rounds256(a, base, 0x40000000, 128, lane);
}

// full hybrid bitonic sort of 2048 (desc) — identical network to rounds 4-12
__device__ __forceinline__ void sort2048(u64* key, int tid, int lane, int wv) {
    const int base = wv * 512;
    for (int k = 2; k <= 512; k <<= 1)
        wave_rounds512(key, base, k, k >> 1, lane);
    __syncthreads();
    #pragma unroll
    for (int p = 0; p < 4; p++) {
        int r = tid + p * 256;
        int low = r & 511, high = (r & ~511) << 1;
        ce_desc(key, high | low, 512, 1024);
    }
    __syncthreads();
    wave_rounds512(key, base, 1024, 256, lane);
    __syncthreads();
    #pragma unroll
    for (int p = 0; p < 4; p++) {
        int r = tid + p * 256;
        int low = r & 1023, high = (r & ~1023) << 1;
        ce_desc(key, high | low, 1024, 2048);
    }
    __syncthreads();
    #pragma unroll
    for (int p = 0; p < 4; p++) {
        int r = tid + p * 256;
        int low = r & 511, high = (r & ~511) << 1;
        ce_desc(key, high | low, 512, 2048);
    }
    __syncthreads();
    wave_rounds512(key, base, 2048, 256, lane);
    __syncthreads();
}

// bitonic sort of 1024 (desc): 4 elems/thread, register-fused j<=2 rounds
__device__ __forceinline__ void sort1024(u64* a, int tid, int lane, int wv) {
    const int t4 = tid * 4;
    const int sb = wv * 256;
    {
        u64 v0 = a[t4], v1 = a[t4 + 1], v2 = a[t4 + 2], v3 = a[t4 + 3];
        ceg(v0, v1, true);
        ceg(v2, v3, false);
        const bool d4 = ((t4 & 4) == 0);
        ceg(v0, v2, d4); ceg(v1, v3, d4);
        ceg(v0, v1, d4); ceg(v2, v3, d4);
        a[t4] = v0; a[t4 + 1] = v1; a[t4 + 2] = v2; a[t4 + 3] = v3;
    }
    __builtin_amdgcn_wave_barrier();
    for (int k = 8; k <= 256; k <<= 1) {
        for (int j = k >> 1; j >= 4; j >>= 1) {
            #pragma unroll
            for (int p = 0; p < 2; p++) {
                int r = lane + p * 64;
                int low = r & (j - 1);
                int high = (r & ~(j - 1)) << 1;
                ce_desc(a, sb + (high | low), j, k);
            }
            __builtin_amdgcn_wave_barrier();
        }
        {
            u64 v0 = a[t4], v1 = a[t4 + 1], v2 = a[t4 + 2], v3 = a[t4 + 3];
            const bool d = ((t4 & k) == 0);
            ceg(v0, v2, d); ceg(v1, v3, d);
            ceg(v0, v1, d); ceg(v2, v3, d);
            a[t4] = v0; a[t4 + 1] = v1; a[t4 + 2] = v2; a[t4 + 3] = v3;
        }
        __builtin_amdgcn_wave_barrier();
    }
    __syncthreads();
    #pragma unroll
    for (int p = 0; p < 2; p++) {
        int r = tid + p * 256;
        int low = r & 255, high = (r & ~255) << 1;
        ce_desc(a, high | low, 256, 512);
    }
    __syncthreads();
    for (int j = 128; j >= 4; j >>= 1) {
        #pragma unroll
        for (int p = 0; p < 2; p++) {
            int r = lane + p * 64;
            int low = r & (j - 1);
            int high = (r & ~(j - 1)) << 1;
            ce_desc(a, sb + (high | low), j, 512);
        }
        __builtin_amdgcn_wave_barrier();
    }
    {
        u64 v0 = a[t4], v1 = a[t4 + 1], v2 = a[t4 + 2], v3 = a[t4 + 3];
        const bool d = ((t4 & 512) == 0);
        ceg(v0, v2, d); ceg(v1, v3, d);
        ceg(v0, v1, d); ceg(v2, v3, d);
        a[t4] = v0; a[t4 + 1] = v1; a[t4 + 2] = v2; a[t4 + 3] = v3;
    }
    __syncthreads();
    #pragma unroll
    for (int p = 0; p < 2; p++) {
        int r = tid + p * 256;
        int low = r & 511, high = (r & ~511) << 1;
        ce_desc(a, high | low, 512, 1024);
    }
    __syncthreads();
    #pragma unroll
    for (int p = 0; p < 2; p++) {
        int r = tid + p * 256;
        int low = r & 255, high = (r & ~255) << 1;
        ce_desc(a, high | low, 256, 1024);
    }
    __syncthreads();
    for (int j = 128; j >= 4; j >>= 1) {
        #pragma unroll
        for (int p = 0; p < 2; p++) {
            int r = lane + p * 64;
            int low = r & (j - 1);
            int high = (r & ~(j - 1)) << 1;
            ce_desc(a, sb + (high | low), j, 1024);
        }
        __builtin_amdgcn_wave_barrier();
    }
    {
        u64 v0 = a[t4], v1 = a[t4 + 1], v2 = a[t4 + 2], v3 = a[t4 + 3];
        const bool d = ((t4 & 1024) == 0);
        ceg(v0, v2, d); ceg(v1, v3, d);
        ceg(v0, v1, d); ceg(v2, v3, d);
        a[t4] = v0; a[t4 + 1] = v1; a[t4 + 2] = v2; a[t4 + 3] = v3;
    }
    __syncthreads();
}

// exact reference-order IoU > 0.5 test (byte-identical to passing rounds 3-13)
__device__ __forceinline__ bool iou_gt_half(float4 a, float aa, float4 b, float ab) {
    float ltx = fmaxf(a.x, b.x);
    float lty = fmaxf(a.y, b.y);
    float rbx = fminf(a.z, b.z);
    float rby = fminf(a.w, b.w);
    float wd = fmaxf(__fsub_rn(rbx, ltx), 0.0f);
    float hd = fmaxf(__fsub_rn(rby, lty), 0.0f);
    float inter = __fmul_rn(wd, hd);
    float uni = __fsub_rn(__fadd_rn(aa, ab), inter);
    float m = fmaxf(uni, 1e-8f);
    float d2 = __fmul_rn(2.0f, inter);
    bool sup = d2 > m;
    if (sup && (__fsub_rn(d2, m) <= __fmul_rn(m, 1.2e-7f)))
        sup = __fdiv_rn(inter, m) > IOU_T;
    return sup;
}

__device__ __forceinline__ float bcast(float v, int sl) {
    return __int_as_float(__builtin_amdgcn_readlane(__float_as_int(v), sl));
}

// R12-verbatim chunked greedy over a desc-sorted array (low 11 bits = 2047-n).
__device__ __forceinline__ int greedy(const u64* cand, int maxch, const float* xb,
        float4* kept_box, float* kept_area, u64* kept_key,
        u64* s_sup, int* s_kept, int* s_done, int tid, int lane, int wv,
        int keptc_in) {
    if (tid == 0) { *s_kept = keptc_in; *s_done = 0; }
    __syncthreads();
    int keptc = keptc_in;
    for (int ch = 0; ch < maxch; ch++) {
        int n = ch * 64 + lane;
        u64 mykey = cand[n];
        float sc = __uint_as_float((u32)(mykey >> 32));
        bool valid = sc > SCORE_T;
        u64 vball = __ballot(valid);
        if (vball == 0ULL) break;

        u32 orig = 2047u - (u32)(mykey & 0x7FFu);
        float4 bx = *(const float4*)(xb + (size_t)orig * ROW);
        float ar = __fmul_rn(__fsub_rn(bx.z, bx.x), __fsub_rn(bx.w, bx.y));

        bool supA = false;
        int t = wv;
        for (; t + 12 < keptc; t += 16) {
            float4 kb0 = kept_box[t],     kb1 = kept_box[t + 4];
            float4 kb2 = kept_box[t + 8], kb3 = kept_box[t + 12];
            float ka0 = kept_area[t],     ka1 = kept_area[t + 4];
            float ka2 = kept_area[t + 8], ka3 = kept_area[t + 12];
            bool s0 = iou_gt_half(bx, ar, kb0, ka0);
            bool s1 = iou_gt_half(bx, ar, kb1, ka1);
            bool s2 = iou_gt_half(bx, ar, kb2, ka2);
            bool s3 = iou_gt_half(bx, ar, kb3, ka3);
            supA = supA | ((s0 | s1) | (s2 | s3));
        }
        for (; t < keptc; t += 4)
            supA = supA | iou_gt_half(bx, ar, kept_box[t], kept_area[t]);
        u64 supm = __ballot(supA);
        if (lane == 0) s_sup[wv] = supm;
        __syncthreads();                   // B1

        if (wv == 0) {
            u64 alive = vball & ~s_sup[0] & ~s_sup[1] & ~s_sup[2] & ~s_sup[3];
            int kept = keptc;
            while (alive) {
                int bsel = (int)__builtin_ctzll(alive);
                if (lane == bsel) {
                    kept_key[kept] = mykey;
                    kept_box[kept] = bx;
                    kept_area[kept] = ar;
                }
                kept++;
                if (kept >= OUT_K) { *s_done = 1; break; }
                alive &= alive - 1;
                if (!alive) break;
                float4 pb = make_float4(bcast(bx.x, bsel), bcast(bx.y, bsel),
                                        bcast(bx.z, bsel), bcast(bx.w, bsel));
                float pa = bcast(ar, bsel);
                alive &= ~__ballot(iou_gt_half(bx, ar, pb, pa));
            }
            if (lane == 0) *s_kept = kept;
        }
        __syncthreads();                   // B2
        keptc = *s_kept;
        if (*s_done) break;
        if (__popcll(vball) < 64) break;
    }
    __syncthreads();
    return keptc;
}

// ---- Kernel A (R12-verbatim): histogram-select -> sort1024 -> greedy ----
__global__ __launch_bounds__(256) void nms_kernel(
        const float* __restrict__ x, u64* __restrict__ cand_key) {
    const int bc = blockIdx.x;
    const int b = bc / NC;
    const int c = bc % NC;
    const int tid = threadIdx.x;
    const int lane = tid & 63;
    const int wv = tid >> 6;

    __shared__ __align__(16) u64 arr[2048];
    u64* comp = arr;
    u32* hist = (u32*)(arr + 1024);
    __shared__ float4 kept_box[OUT_K];
    __shared__ float kept_area[OUT_K];
    __shared__ u64 kept_key[OUT_K];
    __shared__ u64 s_sup[4];
    __shared__ u32 s_wsum[4];
    __shared__ u32 s_cnt, s_m;
    __shared__ int s_kept, s_done, s_thr;

    const float* xb = x + (size_t)b * NN * ROW;

    hist[tid] = 0;
    __syncthreads();
    float scv[8];
    #pragma unroll
    for (int w = 0; w < 8; w++) {
        int n = w * 256 + tid;
        float sc = xb[n * ROW + 4 + c];
        scv[w] = sc;
        int bin = (int)(sc * 256.0f); bin = bin > 255 ? 255 : bin;
        atomicAdd(&hist[bin], 1u);
    }
    __syncthreads();

    u32 cnt_mine = hist[tid];
    u32 incl = cnt_mine;
    #pragma unroll
    for (int off = 1; off < 64; off <<= 1) {
        u32 v = __shfl_down(incl, off, 64);
        if (lane + off < 64) incl += v;
    }
    if (lane == 0) s_wsum[wv] = incl;
    __syncthreads();
    u32 above = 0;
    #pragma unroll
    for (int w = 0; w < 4; w++) above += (w > wv) ? s_wsum[w] : 0;
    const u32 suf = incl + above;

    if (tid == 0) s_thr = 2;
    __syncthreads();
    if (suf >= TGT && suf - cnt_mine < TGT) s_thr = tid;
    __syncthreads();
    int t1 = s_thr;
    if (tid == t1) s_m = suf;
    __syncthreads();
    u32 m_tot = s_m;

    bool fb = (m_tot > POOL);
    int kept = 0;
    if (!fb) {
        if (tid == 0) s_cnt = 0;
        __syncthreads();
        #pragma unroll
        for (int w = 0; w < 8; w++) {
            float sc = scv[w];
            int bin = (int)(sc * 256.0f); bin = bin > 255 ? 255 : bin;
            if (bin >= t1) {
                int n = w * 256 + tid;
                u32 p = atomicAdd(&s_cnt, 1u);
                comp[p] = ((u64)__float_as_uint(sc) << 32) | (u64)(2047 - n);
            }
        }
        __syncthreads();
        for (int i = tid; i < POOL; i += 256) if (i >= (int)m_tot) comp[i] = 0ULL;
        __syncthreads();
        sort1024(comp, tid, lane, wv);
        kept = greedy(comp, POOL / 64, xb, kept_box, kept_area, kept_key,
                      s_sup, &s_kept, &s_done, tid, lane, wv, 0);

        while (kept < OUT_K && t1 > 2) {
            u32 T2 = m_tot + TGT;
            if (tid == 0) s_thr = 2;
            __syncthreads();
            if (suf >= T2 && suf - cnt_mine < T2) s_thr = tid;
            __syncthreads();
            int t2 = s_thr;
            if (tid == t2) s_m = suf;
            __syncthreads();
            u32 m2 = s_m;
            u32 size = m2 - m_tot;
            if (size == 0) break;
            if (size > POOL) { fb = true; break; }
            if (tid == 0) s_cnt = 0;
            __syncthreads();
            #pragma unroll
            for (int w = 0; w < 8; w++) {
                float sc = scv[w];
                int bin = (int)(sc * 256.0f); bin = bin > 255 ? 255 : bin;
                if (bin >= t2 && bin < t1) {
                    int n = w * 256 + tid;
                    u32 p = atomicAdd(&s_cnt, 1u);
                    comp[p] = ((u64)__float_as_uint(sc) << 32) | (u64)(2047 - n);
                }
            }
            __syncthreads();
            for (int i = tid; i < POOL; i += 256) if (i >= (int)size) comp[i] = 0ULL;
            __syncthreads();
            sort1024(comp, tid, lane, wv);
            kept = greedy(comp, POOL / 64, xb, kept_box, kept_area, kept_key,
                          s_sup, &s_kept, &s_done, tid, lane, wv, kept);
            m_tot = m2; t1 = t2;
        }
    }
    if (fb) {
        __syncthreads();
        #pragma unroll
        for (int w = 0; w < 8; w++) {
            int n = w * 256 + tid;
            arr[n] = ((u64)__float_as_uint(scv[w]) << 32) | (u64)(2047 - n);
        }
        __syncthreads();
        sort2048(arr, tid, lane, wv);
        kept = greedy(arr, 32, xb, kept_box, kept_area, kept_key,
                      s_sup, &s_kept, &s_done, tid, lane, wv, 0);
    }

    const int base_o = bc * OUT_K;
    if (tid < OUT_K) {
        u64 ok = 0ULL;
        if (tid < kept) {
            u64 kk = kept_key[tid];
            u32 flat = (u32)(c * OUT_K + tid);
            u32 orig = 2047u - (u32)(kk & 0x7FFu);
            ok = (kk & 0xFFFFFFFF00000000ULL) |
                 ((u64)(0x3FFFu - flat) << 11) | (u64)orig;
        }
        cand_key[base_o + tid] = ok;
    }
}

// ---- Kernel B (R13-verbatim): 8 blocks x 512 threads; 8 waves stream
//      10 runs each, then 3-level tournament -> decode top-200 ----
__global__ __launch_bounds__(512) void topk_kernel(
        const float* __restrict__ x, const u64* __restrict__ cand_key,
        float* __restrict__ out) {
    const int b = blockIdx.x;
    const int tid = threadIdx.x;
    const int lane = tid & 63;
    const int wv = tid >> 6;          // 0..7
    __shared__ u64 seg[4096];         // per-wave 512: A=[0,256) B=[256,512)
    __shared__ u64 acc[2048];
    u64* A = seg + wv * 512;

    const u64* src0 = cand_key + (size_t)(b * NC + wv * 10) * OUT_K;

    A[lane] = src0[lane];
    A[lane + 64] = src0[lane + 64];
    A[lane + 128] = src0[lane + 128];
    A[lane + 192] = (lane + 192 < OUT_K) ? src0[lane + 192] : 0ULL;
    const u64* srcp = src0 + OUT_K;
    u64 r0 = srcp[lane];
    u64 r1 = srcp[lane + 64];
    u64 r2 = srcp[lane + 128];
    u64 r3 = (lane + 192 < OUT_K) ? srcp[lane + 192] : 0ULL;

    for (int i = 1; i < 10; i++) {
        A[256 + lane] = r0;
        A[256 + lane + 64] = r1;
        A[256 + lane + 128] = r2;
        A[256 + lane + 192] = r3;
        if (i + 1 < 10) {
            const u64* srcn = src0 + (size_t)(i + 1) * OUT_K;
            r0 = srcn[lane];
            r1 = srcn[lane + 64];
            r2 = srcn[lane + 128];
            r3 = (lane + 192 < OUT_K) ? srcn[lane + 192] : 0ULL;
        }
        __builtin_amdgcn_wave_barrier();
        pair_merge256(seg, wv * 512, 256, lane);   // A = top-256(A ∪ B)
    }

    #pragma unroll
    for (int p0 = 0; p0 < 4; p0++) {
        int p = lane + p0 * 64;
        acc[wv * 256 + p] = A[p];
    }
    __syncthreads();
    if (wv < 4) pair_merge256(acc, wv * 512, 256, lane);
    __syncthreads();
    if (wv < 2) pair_merge256(acc, wv * 1024, 512, lane);
    __syncthreads();
    if (wv == 0) pair_merge256(acc, 0, 1024, lane);
    __syncthreads();

    const float* xb = x + (size_t)b * NN * ROW;
    if (tid < OUT_K) {
        u64 kk = acc[tid];
        float* o = out + ((size_t)b * OUT_K + tid) * 6;
        if (kk == 0ULL) {
            o[0] = 0.f; o[1] = 0.f; o[2] = 0.f; o[3] = 0.f; o[4] = 0.f; o[5] = 0.f;
        } else {
            u32 lo = (u32)(kk & 0xFFFFFFFFu);
            u32 flat = 0x3FFFu - ((lo >> 11) & 0x3FFFu);
            int cls = flat / OUT_K;
            u32 n = lo & 0x7FFu;
            float scf = __uint_as_float((u32)(kk >> 32));
            float4 bx = *(const float4*)(xb + (size_t)n * ROW);
            o[0] = (float)cls;
            o[1] = scf;
            o[2] = fminf(fmaxf(bx.x, 0.0f), 1.0f);
            o[3] = fminf(fmaxf(bx.y, 0.0f), 1.0f);
            o[4] = fminf(fmaxf(bx.z, 0.0f), 1.0f);
            o[5] = fminf(fmaxf(bx.w, 0.0f), 1.0f);
        }
    }
}

extern "C" void kernel_launch(void* const* d_in, const int* in_sizes, int n_in,
                              void* d_out, int out_size, void* d_ws, size_t ws_size,
                              hipStream_t stream) {
    const float* x = (const float*)d_in[0];
    float* out = (float*)d_out;
    u64* cand_key = (u64*)d_ws;   // 8*80*200*8 = 1,024,000 B
    nms_kernel<<<NB * NC, 256, 0, stream>>>(x, cand_key);
    topk_kernel<<<NB, 512, 0, stream>>>(x, cand_key, out);
}